// Round 6
// baseline (74.015 us; speedup 1.0000x reference)
//
#include <hip/hip_runtime.h>

// db4 decomposition low-pass
static constexpr float H0 = -0.010597401784997278f;
static constexpr float H1 =  0.032883011666982945f;
static constexpr float H2 =  0.030841381835986965f;
static constexpr float H3 = -0.18703481171888114f;
static constexpr float H4 = -0.02798376941698385f;
static constexpr float H5 =  0.6308807679295904f;
static constexpr float H6 =  0.7148465705525415f;
static constexpr float H7 =  0.23037781330885523f;

// Correlation weights, per-level 0.5 folded in (exact pow2 scale).
static constexpr float W0[8] = { 0.5f*H0,  0.5f*H1,  0.5f*H2,  0.5f*H3,
                                 0.5f*H4,  0.5f*H5,  0.5f*H6,  0.5f*H7 };
static constexpr float W1[8] = {-0.5f*H7,  0.5f*H6, -0.5f*H5,  0.5f*H4,
                                -0.5f*H3,  0.5f*H2, -0.5f*H1,  0.5f*H0 };

constexpr int T     = 4096;
constexpr int IPOS  = 1088;   // staged positions (272 granules), [t0-28, t0+1060)
constexpr int BANDF = 1220;   // padded dwords per band buffer (max granule 271)

// pad one 4-float granule per 8 granules (verified conflict-free at granule-stride-1)
static __device__ __forceinline__ int paddr_g(int g) { return (g << 2) + ((g >> 3) << 2); }
static __device__ __forceinline__ int paddr_f(int f) { return f + ((f >> 5) << 2); }

// Streaming-MAC inverse level: thread computes ONE output granule lg (4 floats).
// out[4lg + jp] = sum_k W0[k]*LO[4(lg-D) + jp + D*k] + W1[k]*HI[...]
// Window granules [lg-D, lg-D+NG); all indices compile-time after unroll.
template <int D, int NG>
static __device__ __forceinline__ void level_acc(const float* __restrict__ lo,
                                                 const float* __restrict__ hi,
                                                 int lg, float acc[4])
{
    acc[0] = acc[1] = acc[2] = acc[3] = 0.0f;
#pragma unroll
    for (int j = 0; j < NG; ++j) {
        const int a = paddr_g(lg - D + j);
        const float4 vl = *(const float4*)(lo + a);
        const float4 vh = *(const float4*)(hi + a);
        const float l[4] = {vl.x, vl.y, vl.z, vl.w};
        const float h[4] = {vh.x, vh.y, vh.z, vh.w};
#pragma unroll
        for (int m = 0; m < 4; ++m) {
            const int w = 4 * j + m;
#pragma unroll
            for (int jp = 0; jp < 4; ++jp) {
                const int d = w - jp;
                if (d >= 0 && (d % D) == 0 && (d / D) < 8) {
                    const int k = d / D;
                    acc[jp] = fmaf(W0[k], l[m], acc[jp]);
                    acc[jp] = fmaf(W1[k], h[m], acc[jp]);
                }
            }
        }
    }
}

__global__ __launch_bounds__(256, 4)
void iswt_kernel(const float* __restrict__ in, float* __restrict__ out)
{
    __shared__ __align__(16) float I[IPOS * 4];                     // 17408 B: DMA landing, then r1
    __shared__ __align__(16) float A[BANDF], B[BANDF], C[BANDF], Dd[BANDF]; // 4880 B each

    const int t    = threadIdx.x;
    const int bid  = blockIdx.x;
    const int row  = bid >> 2;
    const int t0   = (bid & 3) << 10;
    const int lane = t & 63;
    const int wv   = t >> 6;

    const float4* __restrict__ src = (const float4*)(in + (size_t)row * (T * 4));

    // ---- stage: DMA 17 chunks x 1KB direct to LDS (interleaved, linear dest) ----
    for (int c = wv; c < 17; c += 4) {
        const int pp = (t0 - 28 + (c << 6) + lane) & (T - 1);       // per-lane global pos (wrap ok)
        __builtin_amdgcn_global_load_lds(
            (const __attribute__((address_space(1))) void*)(src + pp),
            (__attribute__((address_space(3))) void*)(I + (c << 8)),
            16, 0, 0);
    }
    __syncthreads();                                                // drains vmcnt; DMA visible

    // ---- repack: deinterleave 4 bands (b128 read lane-stride 4 dwords: conflict-free) ----
#pragma unroll
    for (int j = 0; j < 4; ++j) {
        const int p = t + (j << 8);
        const float4 v = *(const float4*)(I + (p << 2));
        const int a = paddr_f(p);
        A[a] = v.x;  B[a] = v.y;  C[a] = v.z;  Dd[a] = v.w;
    }
    if (t < 64) {
        const int p = 1024 + t;
        const float4 v = *(const float4*)(I + (p << 2));
        const int a = paddr_f(p);
        A[a] = v.x;  B[a] = v.y;  C[a] = v.z;  Dd[a] = v.w;
    }
    __syncthreads();                                                // I now dead as interleaved

    // ---- Level 1: lo=Dd(cD_1), hi=C(cD_2), D=4 -> r1 into I (padded granule layout), [4,266) ----
    {
        float r[4];
        level_acc<4, 8>(Dd, C, 4 + t, r);
        *(float4*)(I + paddr_g(4 + t)) = make_float4(r[0], r[1], r[2], r[3]);
        if (t < 6) {
            float rt[4];
            level_acc<4, 8>(Dd, C, 260 + t, rt);
            *(float4*)(I + paddr_g(260 + t)) = make_float4(rt[0], rt[1], rt[2], rt[3]);
        }
    }
    __syncthreads();

    // ---- Level 2: lo=I(r1), hi=B(cD_3), D=2 -> r2 into Dd (dead), [6,264) ----
    {
        float r[4];
        level_acc<2, 5>(I, B, 6 + t, r);
        *(float4*)(Dd + paddr_g(6 + t)) = make_float4(r[0], r[1], r[2], r[3]);
        if (t < 2) {
            float rt[4];
            level_acc<2, 5>(I, B, 262 + t, rt);
            *(float4*)(Dd + paddr_g(262 + t)) = make_float4(rt[0], rt[1], rt[2], rt[3]);
        }
    }
    __syncthreads();

    // ---- Level 3: lo=Dd(r2), hi=A(cA), D=1, granules [7,263) -> global ----
    float r3[4];
    level_acc<1, 3>(Dd, A, 7 + t, r3);
    *(float4*)(out + (size_t)row * T + t0 + (t << 2)) =
        make_float4(r3[0], r3[1], r3[2], r3[3]);
}

extern "C" void kernel_launch(void* const* d_in, const int* in_sizes, int n_in,
                              void* d_out, int out_size, void* d_ws, size_t ws_size,
                              hipStream_t stream)
{
    const float* coeffs = (const float*)d_in[0];
    float* out = (float*)d_out;
    const int nrows = in_sizes[0] / (T * 4);    // 4096
    iswt_kernel<<<nrows * 4, 256, 0, stream>>>(coeffs, out);
}